// Round 2
// baseline (70614.899 us; speedup 1.0000x reference)
//
#include <hip/hip_runtime.h>
#include <hip/hip_bf16.h>
#include <cstdint>
#include <cstddef>

// ---------- types & helpers ----------
typedef __attribute__((ext_vector_type(8))) short bf8v;   // 8 x bf16 (raw bits)
typedef __attribute__((ext_vector_type(4))) float f4v;

__device__ __forceinline__ float bf2f(unsigned short u) {
  union { unsigned int i; float f; } v; v.i = ((unsigned int)u) << 16; return v.f;
}
__device__ __forceinline__ unsigned short f2bf(float f) {
  union { float fl; unsigned int i; } v; v.fl = f;
  return (unsigned short)((v.i + 0x7FFFu + ((v.i >> 16) & 1u)) >> 16);
}
__device__ __forceinline__ void gload_lds16(const void* gsrc, void* ldst) {
  __builtin_amdgcn_global_load_lds(
      (const __attribute__((address_space(1))) unsigned int*)gsrc,
      (__attribute__((address_space(3))) unsigned int*)ldst, 16, 0, 0);
}

// ---------- prep kernels ----------
__global__ void cast_bf16_kernel(const float* __restrict__ in, unsigned short* __restrict__ out, int n) {
  int i = blockIdx.x * 256 + threadIdx.x;
  if (i < n) out[i] = f2bf(in[i]);
}

// W: [4][F][O] f32  ->  Wt: [4*O][F] bf16   (row n = k*O+o, col f)
__global__ void transpose_cast_kernel(const float* __restrict__ W, unsigned short* __restrict__ Wt,
                                      int F, int O, int n) {
  int idx = blockIdx.x * 256 + threadIdx.x;
  if (idx >= n) return;
  int f  = idx % F;
  int no = idx / F;
  int k = no / O, o = no % O;
  Wt[idx] = f2bf(W[((size_t)k * F + f) * O + o]);
}

// ---------- embedding -> emb bf16, s-major: emb[(s*96 + r)*512 + o] ----------
__global__ __launch_bounds__(256) void embed_kernel(const float* __restrict__ inp,
                                                    const int* __restrict__ ptypes,
                                                    const float* __restrict__ embW,
                                                    const float* __restrict__ embB,
                                                    unsigned short* __restrict__ emb) {
  int r = blockIdx.x;          // 0..95  (b*6 + a)
  int st = blockIdx.y;         // 0..31  (s tile of 16)
  int b = r / 6, a = r % 6;
  int t = ptypes[r];
  __shared__ float vec[16][102];
  int tid = threadIdx.x;
  for (int i = tid; i < 16 * 102; i += 256) {
    int sl = i / 102, k = i - sl * 102;
    const float* row = inp + ((size_t)(b * 512 + st * 16 + sl)) * 520;
    vec[sl][k] = (k < 72) ? row[30 + a * 73 + 1 + k] : row[k - 72];
  }
  __syncthreads();
  int o0 = tid * 2;
  float acc[16][2];
#pragma unroll
  for (int s = 0; s < 16; ++s) { acc[s][0] = 0.f; acc[s][1] = 0.f; }
  const float* W = embW + (size_t)t * 102 * 512;
  for (int k = 0; k < 102; ++k) {
    float2 w = *(const float2*)&W[k * 512 + o0];
#pragma unroll
    for (int s = 0; s < 16; ++s) {
      float v = vec[s][k];
      acc[s][0] += v * w.x; acc[s][1] += v * w.y;
    }
  }
  float b0v = embB[t * 512 + o0], b1v = embB[t * 512 + o0 + 1];
#pragma unroll
  for (int s = 0; s < 16; ++s) {
    float v0 = fmaxf(acc[s][0] + b0v, 0.f);
    float v1 = fmaxf(acc[s][1] + b1v, 0.f);
    size_t m = ((size_t)(st * 16 + s) * 96 + r) * 512 + o0;
    emb[m] = f2bf(v0); emb[m + 1] = f2bf(v1);
  }
}

// ---------- MFMA bt-GEMM: C[M,N] = A[M,K](bf16) @ B[N,K](bf16)^T (+bias) ----------
template<bool OUT_BF16, bool ADD_BIAS>
__global__ __launch_bounds__(256)
void gemm_bt(const unsigned short* __restrict__ A, const unsigned short* __restrict__ B,
             void* __restrict__ C, const float* __restrict__ bias, int M, int N, int K) {
  __shared__ __align__(16) unsigned short As[128 * 64];
  __shared__ __align__(16) unsigned short Bs[128 * 64];
  const int tid = threadIdx.x;
  const int wave = tid >> 6, lane = tid & 63;
  const int bm = blockIdx.x, bn = blockIdx.y;
  const int wm = (wave >> 1) * 64, wn = (wave & 1) * 64;
  const int lr = lane >> 3, lc = lane & 7;
  f4v acc[4][4];
#pragma unroll
  for (int i = 0; i < 4; ++i)
#pragma unroll
    for (int j = 0; j < 4; ++j) acc[i][j] = (f4v){0.f, 0.f, 0.f, 0.f};
  const unsigned short* Ab = A + (size_t)bm * 128 * K;
  const unsigned short* Bb = B + (size_t)bn * 128 * K;
  const int arow = wave * 32;

  for (int k0 = 0; k0 < K; k0 += 64) {
#pragma unroll
    for (int i = 0; i < 4; ++i) {
      int row = arow + i * 8 + lr;
      gload_lds16(Ab + (size_t)row * K + k0 + lc * 8, &As[(arow + i * 8) * 64]);
      gload_lds16(Bb + (size_t)row * K + k0 + lc * 8, &Bs[(arow + i * 8) * 64]);
    }
    __syncthreads();
#pragma unroll
    for (int kk = 0; kk < 64; kk += 32) {
      bf8v af[4], bv[4];
#pragma unroll
      for (int mi = 0; mi < 4; ++mi)
        af[mi] = *(const bf8v*)&As[(wm + mi * 16 + (lane & 15)) * 64 + kk + (lane >> 4) * 8];
#pragma unroll
      for (int ni = 0; ni < 4; ++ni)
        bv[ni] = *(const bf8v*)&Bs[(wn + ni * 16 + (lane & 15)) * 64 + kk + (lane >> 4) * 8];
#pragma unroll
      for (int mi = 0; mi < 4; ++mi)
#pragma unroll
        for (int ni = 0; ni < 4; ++ni)
          acc[mi][ni] = __builtin_amdgcn_mfma_f32_16x16x32_bf16(af[mi], bv[ni], acc[mi][ni], 0, 0, 0);
    }
    __syncthreads();
  }
  const int r0 = (lane >> 4) * 4, c0 = lane & 15;
#pragma unroll
  for (int mi = 0; mi < 4; ++mi)
#pragma unroll
    for (int ni = 0; ni < 4; ++ni) {
      int col = bn * 128 + wn + ni * 16 + c0;
      float bvv = ADD_BIAS ? bias[col] : 0.f;
#pragma unroll
      for (int j = 0; j < 4; ++j) {
        size_t row = (size_t)bm * 128 + wm + mi * 16 + r0 + j;
        float v = acc[mi][ni][j] + bvv;
        if (OUT_BF16) ((unsigned short*)C)[row * N + col] = f2bf(v);
        else          ((float*)C)[row * N + col] = v;
      }
    }
}

// ---------- GRU step (fp32): gh = h @ W_hh^T, gate math, write h_new + gnn bf16 ----------
// gxc: f32 chunk, rows (s_local*96 + r), 3072 cols
__global__ __launch_bounds__(256) void gru_step(const float* __restrict__ h_in, float* __restrict__ h_out,
                                                const float* __restrict__ gxc,
                                                const float* __restrict__ Whh, const float* __restrict__ bhh,
                                                unsigned short* __restrict__ gnn, int s) {
  __shared__ __align__(16) float hs[32][2][132];
  const int tid = threadIdx.x;
  const int j0 = blockIdx.x * 4, b0 = blockIdx.y * 32;
  const int b_l = tid >> 3, j_l = (tid >> 1) & 3, kh = tid & 1;
  const int j = j0 + j_l;
  float acc0 = 0.f, acc1 = 0.f, acc2 = 0.f;
  for (int kc = 0; kc < 4; ++kc) {
#pragma unroll
    for (int i = 0; i < 8; ++i) {
      int v = tid + i * 256;
      int row = v >> 6, c4 = v & 63, khs = c4 >> 5, cc = c4 & 31;
      float4 hv = *(const float4*)&h_in[(size_t)(b0 + row) * 1024 + khs * 512 + kc * 128 + cc * 4];
      *(float4*)&hs[row][khs][cc * 4] = hv;
    }
    __syncthreads();
    const int kbase = kh * 512 + kc * 128;
    const float* Wr = Whh + (size_t)(j) * 1024 + kbase;
    const float* Wz = Whh + (size_t)(1024 + j) * 1024 + kbase;
    const float* Wn = Whh + (size_t)(2048 + j) * 1024 + kbase;
#pragma unroll 4
    for (int k4 = 0; k4 < 32; ++k4) {
      float4 hv = *(const float4*)&hs[b_l][kh][k4 * 4];
      float4 wr = *(const float4*)&Wr[k4 * 4];
      float4 wz = *(const float4*)&Wz[k4 * 4];
      float4 wn = *(const float4*)&Wn[k4 * 4];
      acc0 += hv.x * wr.x + hv.y * wr.y + hv.z * wr.z + hv.w * wr.w;
      acc1 += hv.x * wz.x + hv.y * wz.y + hv.z * wz.z + hv.w * wz.w;
      acc2 += hv.x * wn.x + hv.y * wn.y + hv.z * wn.z + hv.w * wn.w;
    }
    __syncthreads();
  }
  acc0 += __shfl_xor(acc0, 1);
  acc1 += __shfl_xor(acc1, 1);
  acc2 += __shfl_xor(acc2, 1);
  if (kh == 0) {
    int rr = b0 + b_l;
    size_t gxi = ((size_t)((s & 63) * 96 + rr)) * 3072 + j;
    float xr = gxc[gxi], xz = gxc[gxi + 1024], xn = gxc[gxi + 2048];
    float hr = acc0 + bhh[j], hz = acc1 + bhh[1024 + j], hn = acc2 + bhh[2048 + j];
    float rg = 1.f / (1.f + expf(-(xr + hr)));
    float zg = 1.f / (1.f + expf(-(xz + hz)));
    float ng = tanhf(xn + rg * hn);
    float hold = h_in[(size_t)rr * 1024 + j];
    float hnew = (1.f - zg) * ng + zg * hold;
    h_out[(size_t)rr * 1024 + j] = hnew;
    int bb = rr / 6, aa = rr % 6;
    gnn[(((size_t)bb * 512 + s) * 6 + aa) * 1024 + j] = f2bf(hnew);
  }
}

// ---------- GAT0 attention+combine: per (b,s): Wh bf16 (4 heads,6 nodes,256) -> g0 bf16 ----------
__global__ __launch_bounds__(256) void gat0_combine(const unsigned short* __restrict__ Wh,
                                                    const float* __restrict__ a0,
                                                    unsigned short* __restrict__ g0) {
  int bs = blockIdx.x;  // b*512+s
  __shared__ __align__(16) float W[6][1024];
  int tid = threadIdx.x;
  const unsigned short* src = Wh + (size_t)bs * 6144;
  for (int i = tid; i < 768; i += 256) {
    bf8v v = ((const bf8v*)src)[i];
    float* dst = &W[0][0] + i * 8;
#pragma unroll
    for (int j = 0; j < 8; ++j) dst[j] = bf2f((unsigned short)v[j]);
  }
  __syncthreads();
  int k = tid >> 6, l = tid & 63;
  float ai[4], aj[4];
#pragma unroll
  for (int i = 0; i < 4; ++i) { ai[i] = a0[k * 512 + l + i * 64]; aj[i] = a0[k * 512 + 256 + l + i * 64]; }
  float ei[6], ej[6];
#pragma unroll
  for (int n = 0; n < 6; ++n) {
    float pi = 0.f, pj = 0.f;
#pragma unroll
    for (int i = 0; i < 4; ++i) { float w = W[n][k * 256 + l + i * 64]; pi += w * ai[i]; pj += w * aj[i]; }
    for (int off = 32; off; off >>= 1) { pi += __shfl_xor(pi, off); pj += __shfl_xor(pj, off); }
    ei[n] = pi; ej[n] = pj;
  }
  float attn[6][6];
#pragma unroll
  for (int n = 0; n < 6; ++n) {
    float e[6]; float mx = -1e30f;
#pragma unroll
    for (int m = 0; m < 6; ++m) { e[m] = fmaxf(ei[n] + ej[m], 0.f); mx = fmaxf(mx, e[m]); }
    float ssum = 0.f;
#pragma unroll
    for (int m = 0; m < 6; ++m) { e[m] = expf(e[m] - mx); ssum += e[m]; }
    float inv = 1.f / ssum;
#pragma unroll
    for (int m = 0; m < 6; ++m) attn[n][m] = e[m] * inv;
  }
#pragma unroll
  for (int n = 0; n < 6; ++n)
#pragma unroll
    for (int i = 0; i < 4; ++i) {
      int o = l + i * 64;
      float accv = 0.f;
#pragma unroll
      for (int m = 0; m < 6; ++m) accv += attn[n][m] * W[m][k * 256 + o];
      float v = accv > 0.f ? accv : expm1f(accv);
      g0[((size_t)bs * 6 + n) * 1024 + k * 256 + o] = f2bf(v);
    }
}

// ---------- GAT1 attention+combine, node0 only -> feat0 f32 (b,s, k*128+o) ----------
__global__ __launch_bounds__(256) void gat1_combine(const unsigned short* __restrict__ Wh,
                                                    const float* __restrict__ a1,
                                                    float* __restrict__ feat0) {
  int bs = blockIdx.x;
  __shared__ __align__(16) float W[6][512];
  int tid = threadIdx.x;
  const unsigned short* src = Wh + (size_t)bs * 3072;
  for (int i = tid; i < 384; i += 256) {
    bf8v v = ((const bf8v*)src)[i];
    float* dst = &W[0][0] + i * 8;
#pragma unroll
    for (int j = 0; j < 8; ++j) dst[j] = bf2f((unsigned short)v[j]);
  }
  __syncthreads();
  int k = tid >> 6, l = tid & 63;
  float ai[2], aj[2];
#pragma unroll
  for (int i = 0; i < 2; ++i) { ai[i] = a1[k * 256 + l + i * 64]; aj[i] = a1[k * 256 + 128 + l + i * 64]; }
  float pi = 0.f;
#pragma unroll
  for (int i = 0; i < 2; ++i) pi += W[0][k * 128 + l + i * 64] * ai[i];
  for (int off = 32; off; off >>= 1) pi += __shfl_xor(pi, off);
  float ei0 = pi;
  float ej[6];
#pragma unroll
  for (int m = 0; m < 6; ++m) {
    float pj = 0.f;
#pragma unroll
    for (int i = 0; i < 2; ++i) pj += W[m][k * 128 + l + i * 64] * aj[i];
    for (int off = 32; off; off >>= 1) pj += __shfl_xor(pj, off);
    ej[m] = pj;
  }
  float e[6]; float mx = -1e30f;
#pragma unroll
  for (int m = 0; m < 6; ++m) { e[m] = fmaxf(ei0 + ej[m], 0.f); mx = fmaxf(mx, e[m]); }
  float ssum = 0.f;
#pragma unroll
  for (int m = 0; m < 6; ++m) { e[m] = expf(e[m] - mx); ssum += e[m]; }
  float inv = 1.f / ssum;
#pragma unroll
  for (int i = 0; i < 2; ++i) {
    int o = l + i * 64;
    float accv = 0.f;
#pragma unroll
    for (int m = 0; m < 6; ++m) accv += (e[m] * inv) * W[m][k * 128 + o];
    feat0[(size_t)bs * 512 + k * 128 + o] = accv > 0.f ? accv : expm1f(accv);
  }
}

// ---------- actor head ----------
__global__ __launch_bounds__(256) void actor_kernel(const float* __restrict__ feat0, const int* __restrict__ ptypes,
                                                    const float* __restrict__ aW1, const float* __restrict__ ab1,
                                                    const float* __restrict__ aW2, const float* __restrict__ ab2,
                                                    const float* __restrict__ inp, float* __restrict__ out) {
  int b = blockIdx.x, st = blockIdx.y;
  int t0 = ptypes[b * 6];
  __shared__ __align__(16) float ft[16][512];
  __shared__ __align__(16) float h1[16][256];
  int tid = threadIdx.x;
  const float* src = feat0 + ((size_t)b * 512 + st * 16) * 512;
  for (int i = tid; i < 16 * 512 / 4; i += 256)
    ((float4*)&ft[0][0])[i] = ((const float4*)src)[i];
  __syncthreads();
  int o = tid;
  float acc[16];
#pragma unroll
  for (int s = 0; s < 16; ++s) acc[s] = 0.f;
  const float* W1p = aW1 + (size_t)t0 * 512 * 256;
  for (int i = 0; i < 512; ++i) {
    float w = W1p[i * 256 + o];
#pragma unroll
    for (int s = 0; s < 16; ++s) acc[s] += ft[s][i] * w;
  }
  float bb = ab1[t0 * 256 + o];
#pragma unroll
  for (int s = 0; s < 16; ++s) h1[s][o] = fmaxf(acc[s] + bb, 0.f);
  __syncthreads();
  const float* W2p = aW2 + (size_t)t0 * 256 * 52;
  for (int idx = tid; idx < 16 * 52; idx += 256) {
    int s = idx / 52, d = idx - s * 52;
    float a = ab2[t0 * 52 + d];
    for (int i = 0; i < 256; ++i) a += h1[s][i] * W2p[i * 52 + d];
    int sg = st * 16 + s;
    float m = inp[((size_t)b * 512 + sg) * 520 + 468 + d];
    out[((size_t)b * 512 + sg) * 52 + d] = (m != 0.f) ? a : 0.f;
  }
}

// ---------- launch ----------
extern "C" void kernel_launch(void* const* d_in, const int* in_sizes, int n_in,
                              void* d_out, int out_size, void* d_ws, size_t ws_size,
                              hipStream_t stream) {
  const float* inputs = (const float*)d_in[0];
  const float* state  = (const float*)d_in[1];
  const int*   ptypes = (const int*)d_in[2];
  const float* emb_W  = (const float*)d_in[3];
  const float* emb_b  = (const float*)d_in[4];
  const float* W_ih   = (const float*)d_in[5];
  const float* W_hh   = (const float*)d_in[6];
  const float* b_ih   = (const float*)d_in[7];
  const float* b_hh   = (const float*)d_in[8];
  const float* W0     = (const float*)d_in[9];
  const float* a0     = (const float*)d_in[10];
  const float* W1     = (const float*)d_in[11];
  const float* a1     = (const float*)d_in[12];
  const float* aW1    = (const float*)d_in[13];
  const float* ab1    = (const float*)d_in[14];
  const float* aW2    = (const float*)d_in[15];
  const float* ab2    = (const float*)d_in[16];

  char* ws = (char*)d_ws;
  // phase A/B  (peak 233,570,304 B)
  unsigned short* emb  = (unsigned short*)(ws + 0);            // 50,331,648 B  [s][r][512] bf16
  float*          gxc  = (float*)(ws + 50331648);              // 75,497,472 B  one 64-step chunk, f32
  unsigned short* gnn  = (unsigned short*)(ws + 125829120);    // 100,663,296 B
  float* h0            = (float*)(ws + 226492416);             // 393,216 B
  float* h1b           = (float*)(ws + 226885632);             // 393,216 B
  unsigned short* Wihb = (unsigned short*)(ws + 227278848);    // 3,145,728 B
  unsigned short* W0t  = (unsigned short*)(ws + 230424576);    // 2,097,152 B
  unsigned short* W1t  = (unsigned short*)(ws + 232521728);    // 1,048,576 B
  // phase C overlays
  unsigned short* Wh0  = (unsigned short*)(ws + 0);            // 100,663,296 B (emb+gxc dead)
  unsigned short* g0   = (unsigned short*)(ws + 125829120);    // 100,663,296 B (gnn dead)
  unsigned short* Wh1  = (unsigned short*)(ws + 0);            //  50,331,648 B (Wh0 dead)
  float*          feat = (float*)(ws + 50331648);              //  16,777,216 B (Wh0 dead)

  float* logits = (float*)d_out;
  float* hfin   = (float*)d_out + 16 * 512 * 52;

  cast_bf16_kernel<<<6144, 256, 0, stream>>>(W_ih, Wihb, 3072 * 512);
  transpose_cast_kernel<<<4096, 256, 0, stream>>>(W0, W0t, 1024, 256, 4 * 1024 * 256);
  transpose_cast_kernel<<<2048, 256, 0, stream>>>(W1, W1t, 1024, 128, 4 * 1024 * 128);
  hipMemcpyAsync(h0, state, 96 * 1024 * sizeof(float), hipMemcpyDeviceToDevice, stream);

  embed_kernel<<<dim3(96, 32), 256, 0, stream>>>(inputs, ptypes, emb_W, emb_b, emb);

  for (int c = 0; c < 8; ++c) {
    gemm_bt<false, true><<<dim3(48, 24), 256, 0, stream>>>(
        emb + (size_t)c * 6144 * 512, Wihb, gxc, b_ih, 6144, 3072, 512);
    for (int sl = 0; sl < 64; ++sl) {
      int s = c * 64 + sl;
      const float* hin = (s & 1) ? h1b : h0;
      float* hout      = (s & 1) ? h0 : h1b;
      gru_step<<<dim3(256, 3), 256, 0, stream>>>(hin, hout, gxc, W_hh, b_hh, gnn, s);
    }
  }
  // final h is in h0 (s=511 odd -> hout = h0)

  gemm_bt<true, false><<<dim3(384, 8), 256, 0, stream>>>(gnn, W0t, Wh0, nullptr, 49152, 1024, 1024);
  gat0_combine<<<8192, 256, 0, stream>>>(Wh0, a0, g0);
  gemm_bt<true, false><<<dim3(384, 4), 256, 0, stream>>>(g0, W1t, Wh1, nullptr, 49152, 512, 1024);
  gat1_combine<<<8192, 256, 0, stream>>>(Wh1, a1, feat);
  actor_kernel<<<dim3(16, 32), 256, 0, stream>>>(feat, ptypes, aW1, ab1, aW2, ab2, inputs, logits);
  hipMemcpyAsync(hfin, h0, 96 * 1024 * sizeof(float), hipMemcpyDeviceToDevice, stream);
}

// Round 3
// 10357.443 us; speedup vs baseline: 6.8178x; 6.8178x over previous
//
#include <hip/hip_runtime.h>
#include <hip/hip_bf16.h>
#include <cstdint>
#include <cstddef>

// ---------- types & helpers ----------
typedef __attribute__((ext_vector_type(8))) short bf8v;   // 8 x bf16 (raw bits)
typedef __attribute__((ext_vector_type(4))) float f4v;

__device__ __forceinline__ float bf2f(unsigned short u) {
  union { unsigned int i; float f; } v; v.i = ((unsigned int)u) << 16; return v.f;
}
__device__ __forceinline__ unsigned short f2bf(float f) {
  union { float fl; unsigned int i; } v; v.fl = f;
  return (unsigned short)((v.i + 0x7FFFu + ((v.i >> 16) & 1u)) >> 16);
}
__device__ __forceinline__ void gload_lds16(const void* gsrc, void* ldst) {
  __builtin_amdgcn_global_load_lds(
      (const __attribute__((address_space(1))) unsigned int*)gsrc,
      (__attribute__((address_space(3))) unsigned int*)ldst, 16, 0, 0);
}

// ---------- prep kernels ----------
__global__ void cast_bf16_kernel(const float* __restrict__ in, unsigned short* __restrict__ out, int n) {
  int i = blockIdx.x * 256 + threadIdx.x;
  if (i < n) out[i] = f2bf(in[i]);
}

// W: [4][F][O] f32  ->  Wt: [4*O][F] bf16   (row n = k*O+o, col f)
__global__ void transpose_cast_kernel(const float* __restrict__ W, unsigned short* __restrict__ Wt,
                                      int F, int O, int n) {
  int idx = blockIdx.x * 256 + threadIdx.x;
  if (idx >= n) return;
  int f  = idx % F;
  int no = idx / F;
  int k = no / O, o = no % O;
  Wt[idx] = f2bf(W[((size_t)k * F + f) * O + o]);
}

// ---------- embedding -> emb bf16, s-major: emb[(s*96 + r)*512 + o] ----------
__global__ __launch_bounds__(256) void embed_kernel(const float* __restrict__ inp,
                                                    const int* __restrict__ ptypes,
                                                    const float* __restrict__ embW,
                                                    const float* __restrict__ embB,
                                                    unsigned short* __restrict__ emb) {
  int r = blockIdx.x;          // 0..95  (b*6 + a)
  int st = blockIdx.y;         // 0..31  (s tile of 16)
  int b = r / 6, a = r % 6;
  int t = ptypes[r];
  __shared__ float vec[16][102];
  int tid = threadIdx.x;
  for (int i = tid; i < 16 * 102; i += 256) {
    int sl = i / 102, k = i - sl * 102;
    const float* row = inp + ((size_t)(b * 512 + st * 16 + sl)) * 520;
    vec[sl][k] = (k < 72) ? row[30 + a * 73 + 1 + k] : row[k - 72];
  }
  __syncthreads();
  int o0 = tid * 2;
  float acc[16][2];
#pragma unroll
  for (int s = 0; s < 16; ++s) { acc[s][0] = 0.f; acc[s][1] = 0.f; }
  const float* W = embW + (size_t)t * 102 * 512;
  for (int k = 0; k < 102; ++k) {
    float2 w = *(const float2*)&W[k * 512 + o0];
#pragma unroll
    for (int s = 0; s < 16; ++s) {
      float v = vec[s][k];
      acc[s][0] += v * w.x; acc[s][1] += v * w.y;
    }
  }
  float b0v = embB[t * 512 + o0], b1v = embB[t * 512 + o0 + 1];
#pragma unroll
  for (int s = 0; s < 16; ++s) {
    float v0 = fmaxf(acc[s][0] + b0v, 0.f);
    float v1 = fmaxf(acc[s][1] + b1v, 0.f);
    size_t m = ((size_t)(st * 16 + s) * 96 + r) * 512 + o0;
    emb[m] = f2bf(v0); emb[m + 1] = f2bf(v1);
  }
}

// ---------- MFMA bt-GEMM: C[M,N] = A[M,K](bf16) @ B[N,K](bf16)^T (+bias) ----------
template<bool OUT_BF16, bool ADD_BIAS>
__global__ __launch_bounds__(256)
void gemm_bt(const unsigned short* __restrict__ A, const unsigned short* __restrict__ B,
             void* __restrict__ C, const float* __restrict__ bias, int M, int N, int K) {
  __shared__ __align__(16) unsigned short As[128 * 64];
  __shared__ __align__(16) unsigned short Bs[128 * 64];
  const int tid = threadIdx.x;
  const int wave = tid >> 6, lane = tid & 63;
  const int bm = blockIdx.x, bn = blockIdx.y;
  const int wm = (wave >> 1) * 64, wn = (wave & 1) * 64;
  const int lr = lane >> 3, lc = lane & 7;
  f4v acc[4][4];
#pragma unroll
  for (int i = 0; i < 4; ++i)
#pragma unroll
    for (int j = 0; j < 4; ++j) acc[i][j] = (f4v){0.f, 0.f, 0.f, 0.f};
  const unsigned short* Ab = A + (size_t)bm * 128 * K;
  const unsigned short* Bb = B + (size_t)bn * 128 * K;
  const int arow = wave * 32;

  for (int k0 = 0; k0 < K; k0 += 64) {
#pragma unroll
    for (int i = 0; i < 4; ++i) {
      int row = arow + i * 8 + lr;
      gload_lds16(Ab + (size_t)row * K + k0 + lc * 8, &As[(arow + i * 8) * 64]);
      gload_lds16(Bb + (size_t)row * K + k0 + lc * 8, &Bs[(arow + i * 8) * 64]);
    }
    __syncthreads();
#pragma unroll
    for (int kk = 0; kk < 64; kk += 32) {
      bf8v af[4], bv[4];
#pragma unroll
      for (int mi = 0; mi < 4; ++mi)
        af[mi] = *(const bf8v*)&As[(wm + mi * 16 + (lane & 15)) * 64 + kk + (lane >> 4) * 8];
#pragma unroll
      for (int ni = 0; ni < 4; ++ni)
        bv[ni] = *(const bf8v*)&Bs[(wn + ni * 16 + (lane & 15)) * 64 + kk + (lane >> 4) * 8];
#pragma unroll
      for (int mi = 0; mi < 4; ++mi)
#pragma unroll
        for (int ni = 0; ni < 4; ++ni)
          acc[mi][ni] = __builtin_amdgcn_mfma_f32_16x16x32_bf16(af[mi], bv[ni], acc[mi][ni], 0, 0, 0);
    }
    __syncthreads();
  }
  const int r0 = (lane >> 4) * 4, c0 = lane & 15;
#pragma unroll
  for (int mi = 0; mi < 4; ++mi)
#pragma unroll
    for (int ni = 0; ni < 4; ++ni) {
      int col = bn * 128 + wn + ni * 16 + c0;
      float bvv = ADD_BIAS ? bias[col] : 0.f;
#pragma unroll
      for (int j = 0; j < 4; ++j) {
        size_t row = (size_t)bm * 128 + wm + mi * 16 + r0 + j;
        float v = acc[mi][ni][j] + bvv;
        if (OUT_BF16) ((unsigned short*)C)[row * N + col] = f2bf(v);
        else          ((float*)C)[row * N + col] = v;
      }
    }
}

// ---------- persistent GRU chunk: 32 steps, weights resident in VGPR, grid-barrier per step ----------
// 64 blocks x 256 threads. Block bx owns j-slice [bx*16, bx*16+16).
// Wave wv (0..3) owns K-slice [wv*256, wv*256+256).
// h_bf: [2][96][1024] bf16 double buffer. h_f32 state held in registers across steps.
__global__ __launch_bounds__(256, 1) void gru_chunk(const unsigned short* __restrict__ Whh_bf,
                                                    const float* __restrict__ gxc,
                                                    const float* __restrict__ bhh,
                                                    unsigned short* __restrict__ h_bf,
                                                    float* __restrict__ h_f32,
                                                    unsigned short* __restrict__ gnn,
                                                    int s_base, int* __restrict__ bar) {
  const int tid = threadIdx.x, lane = tid & 63, wv = tid >> 6;
  const int j0 = blockIdx.x * 16;
  const int l15 = lane & 15, lhi = lane >> 4;

  // resident weight fragments: 3 gates x 8 k-slices, each 8 bf16 (B-operand, rows = Whh rows)
  bf8v wfrag[3][8];
#pragma unroll
  for (int g = 0; g < 3; ++g)
#pragma unroll
    for (int kk = 0; kk < 8; ++kk)
      wfrag[g][kk] = *(const bf8v*)&Whh_bf[((size_t)(g * 1024 + j0 + l15)) * 1024 + wv * 256 + kk * 32 + lhi * 8];

  // per-thread f32 h state: 6 elems, (r = (tid>>4) + 16*i, j = j0 + (tid&15))
  const int j_l = tid & 15, rb = tid >> 4;
  float hreg[6];
#pragma unroll
  for (int i = 0; i < 6; ++i) hreg[i] = h_f32[(size_t)(rb + 16 * i) * 1024 + j0 + j_l];

  float bh[3];
#pragma unroll
  for (int g = 0; g < 3; ++g) bh[g] = bhh[g * 1024 + j0 + j_l];

  __shared__ float red[4][96][49];
  int gen = s_base;   // global barrier generation (monotonic across chunks)

  for (int sl = 0; sl < 32; ++sl) {
    const unsigned short* hb = h_bf + (size_t)(sl & 1) * 98304;
    unsigned short* hbn      = h_bf + (size_t)((sl & 1) ^ 1) * 98304;

    f4v acc[6][3];
#pragma unroll
    for (int mt = 0; mt < 6; ++mt)
#pragma unroll
      for (int g = 0; g < 3; ++g) acc[mt][g] = (f4v){0.f, 0.f, 0.f, 0.f};

#pragma unroll
    for (int kk = 0; kk < 8; ++kk) {
      bf8v a[6];
#pragma unroll
      for (int mt = 0; mt < 6; ++mt)
        a[mt] = *(const bf8v*)&hb[(size_t)(mt * 16 + l15) * 1024 + wv * 256 + kk * 32 + lhi * 8];
#pragma unroll
      for (int mt = 0; mt < 6; ++mt)
#pragma unroll
        for (int g = 0; g < 3; ++g)
          acc[mt][g] = __builtin_amdgcn_mfma_f32_16x16x32_bf16(a[mt], wfrag[g][kk], acc[mt][g], 0, 0, 0);
    }

    // write K-partials to LDS
#pragma unroll
    for (int mt = 0; mt < 6; ++mt)
#pragma unroll
      for (int g = 0; g < 3; ++g)
#pragma unroll
        for (int j = 0; j < 4; ++j)
          red[wv][mt * 16 + lhi * 4 + j][g * 16 + l15] = acc[mt][g][j];
    __syncthreads();

    // gather + gate math + state update
#pragma unroll
    for (int i = 0; i < 6; ++i) {
      int r = rb + 16 * i;
      float gh[3];
#pragma unroll
      for (int g = 0; g < 3; ++g)
        gh[g] = red[0][r][g * 16 + j_l] + red[1][r][g * 16 + j_l] +
                red[2][r][g * 16 + j_l] + red[3][r][g * 16 + j_l] + bh[g];
      size_t gxi = ((size_t)sl * 96 + r) * 3072 + j0 + j_l;
      float xr = gxc[gxi], xz = gxc[gxi + 1024], xn = gxc[gxi + 2048];
      float rg = 1.f / (1.f + expf(-(xr + gh[0])));
      float zg = 1.f / (1.f + expf(-(xz + gh[1])));
      float ng = tanhf(xn + rg * gh[2]);
      float hnew = (1.f - zg) * ng + zg * hreg[i];
      hreg[i] = hnew;
      unsigned short hb16 = f2bf(hnew);
      hbn[(size_t)r * 1024 + j0 + j_l] = hb16;
      int bb = r / 6, aa = r - bb * 6;
      gnn[(((size_t)bb * 512 + s_base + sl) * 6 + aa) * 1024 + j0 + j_l] = hb16;
    }

    // grid barrier (device-scope)
    __syncthreads();
    if (tid == 0) {
      __threadfence();
      int arr = __hip_atomic_fetch_add(&bar[0], 1, __ATOMIC_ACQ_REL, __HIP_MEMORY_SCOPE_AGENT);
      if (arr == 63) {
        __hip_atomic_store(&bar[0], 0, __ATOMIC_RELAXED, __HIP_MEMORY_SCOPE_AGENT);
        __hip_atomic_fetch_add(&bar[1], 1, __ATOMIC_ACQ_REL, __HIP_MEMORY_SCOPE_AGENT);
      } else {
        while (__hip_atomic_load(&bar[1], __ATOMIC_ACQUIRE, __HIP_MEMORY_SCOPE_AGENT) <= gen) {}
      }
      __threadfence();
    }
    gen++;
    __syncthreads();
  }

#pragma unroll
  for (int i = 0; i < 6; ++i) h_f32[(size_t)(rb + 16 * i) * 1024 + j0 + j_l] = hreg[i];
}

// ---------- GAT0 attention+combine (chunk-local bs) ----------
__global__ __launch_bounds__(256) void gat0_combine(const unsigned short* __restrict__ Wh,
                                                    const float* __restrict__ a0,
                                                    unsigned short* __restrict__ g0) {
  int bs = blockIdx.x;
  __shared__ __align__(16) float W[6][1024];
  int tid = threadIdx.x;
  const unsigned short* src = Wh + (size_t)bs * 6144;
  for (int i = tid; i < 768; i += 256) {
    bf8v v = ((const bf8v*)src)[i];
    float* dst = &W[0][0] + i * 8;
#pragma unroll
    for (int j = 0; j < 8; ++j) dst[j] = bf2f((unsigned short)v[j]);
  }
  __syncthreads();
  int k = tid >> 6, l = tid & 63;
  float ai[4], aj[4];
#pragma unroll
  for (int i = 0; i < 4; ++i) { ai[i] = a0[k * 512 + l + i * 64]; aj[i] = a0[k * 512 + 256 + l + i * 64]; }
  float ei[6], ej[6];
#pragma unroll
  for (int n = 0; n < 6; ++n) {
    float pi = 0.f, pj = 0.f;
#pragma unroll
    for (int i = 0; i < 4; ++i) { float w = W[n][k * 256 + l + i * 64]; pi += w * ai[i]; pj += w * aj[i]; }
    for (int off = 32; off; off >>= 1) { pi += __shfl_xor(pi, off); pj += __shfl_xor(pj, off); }
    ei[n] = pi; ej[n] = pj;
  }
  float attn[6][6];
#pragma unroll
  for (int n = 0; n < 6; ++n) {
    float e[6]; float mx = -1e30f;
#pragma unroll
    for (int m = 0; m < 6; ++m) { e[m] = fmaxf(ei[n] + ej[m], 0.f); mx = fmaxf(mx, e[m]); }
    float ssum = 0.f;
#pragma unroll
    for (int m = 0; m < 6; ++m) { e[m] = expf(e[m] - mx); ssum += e[m]; }
    float inv = 1.f / ssum;
#pragma unroll
    for (int m = 0; m < 6; ++m) attn[n][m] = e[m] * inv;
  }
#pragma unroll
  for (int n = 0; n < 6; ++n)
#pragma unroll
    for (int i = 0; i < 4; ++i) {
      int o = l + i * 64;
      float accv = 0.f;
#pragma unroll
      for (int m = 0; m < 6; ++m) accv += attn[n][m] * W[m][k * 256 + o];
      float v = accv > 0.f ? accv : expm1f(accv);
      g0[((size_t)bs * 6 + n) * 1024 + k * 256 + o] = f2bf(v);
    }
}

// ---------- GAT1 attention+combine, node0 only (chunk-local bs) ----------
__global__ __launch_bounds__(256) void gat1_combine(const unsigned short* __restrict__ Wh,
                                                    const float* __restrict__ a1,
                                                    float* __restrict__ feat0) {
  int bs = blockIdx.x;
  __shared__ __align__(16) float W[6][512];
  int tid = threadIdx.x;
  const unsigned short* src = Wh + (size_t)bs * 3072;
  for (int i = tid; i < 384; i += 256) {
    bf8v v = ((const bf8v*)src)[i];
    float* dst = &W[0][0] + i * 8;
#pragma unroll
    for (int j = 0; j < 8; ++j) dst[j] = bf2f((unsigned short)v[j]);
  }
  __syncthreads();
  int k = tid >> 6, l = tid & 63;
  float ai[2], aj[2];
#pragma unroll
  for (int i = 0; i < 2; ++i) { ai[i] = a1[k * 256 + l + i * 64]; aj[i] = a1[k * 256 + 128 + l + i * 64]; }
  float pi = 0.f;
#pragma unroll
  for (int i = 0; i < 2; ++i) pi += W[0][k * 128 + l + i * 64] * ai[i];
  for (int off = 32; off; off >>= 1) pi += __shfl_xor(pi, off);
  float ei0 = pi;
  float ej[6];
#pragma unroll
  for (int m = 0; m < 6; ++m) {
    float pj = 0.f;
#pragma unroll
    for (int i = 0; i < 2; ++i) pj += W[m][k * 128 + l + i * 64] * aj[i];
    for (int off = 32; off; off >>= 1) pj += __shfl_xor(pj, off);
    ej[m] = pj;
  }
  float e[6]; float mx = -1e30f;
#pragma unroll
  for (int m = 0; m < 6; ++m) { e[m] = fmaxf(ei0 + ej[m], 0.f); mx = fmaxf(mx, e[m]); }
  float ssum = 0.f;
#pragma unroll
  for (int m = 0; m < 6; ++m) { e[m] = expf(e[m] - mx); ssum += e[m]; }
  float inv = 1.f / ssum;
#pragma unroll
  for (int i = 0; i < 2; ++i) {
    int o = l + i * 64;
    float accv = 0.f;
#pragma unroll
    for (int m = 0; m < 6; ++m) accv += (e[m] * inv) * W[m][k * 128 + o];
    feat0[(size_t)bs * 512 + k * 128 + o] = accv > 0.f ? accv : expm1f(accv);
  }
}

// ---------- actor head (b-chunked: b_global = b0 + blockIdx.x) ----------
__global__ __launch_bounds__(256) void actor_kernel(const float* __restrict__ feat0, const int* __restrict__ ptypes,
                                                    const float* __restrict__ aW1, const float* __restrict__ ab1,
                                                    const float* __restrict__ aW2, const float* __restrict__ ab2,
                                                    const float* __restrict__ inp, float* __restrict__ out, int b0) {
  int bl = blockIdx.x, st = blockIdx.y;
  int b = b0 + bl;
  int t0 = ptypes[b * 6];
  __shared__ __align__(16) float ft[16][512];
  __shared__ __align__(16) float h1[16][256];
  int tid = threadIdx.x;
  const float* src = feat0 + ((size_t)bl * 512 + st * 16) * 512;
  for (int i = tid; i < 16 * 512 / 4; i += 256)
    ((float4*)&ft[0][0])[i] = ((const float4*)src)[i];
  __syncthreads();
  int o = tid;
  float acc[16];
#pragma unroll
  for (int s = 0; s < 16; ++s) acc[s] = 0.f;
  const float* W1p = aW1 + (size_t)t0 * 512 * 256;
  for (int i = 0; i < 512; ++i) {
    float w = W1p[i * 256 + o];
#pragma unroll
    for (int s = 0; s < 16; ++s) acc[s] += ft[s][i] * w;
  }
  float bb = ab1[t0 * 256 + o];
#pragma unroll
  for (int s = 0; s < 16; ++s) h1[s][o] = fmaxf(acc[s] + bb, 0.f);
  __syncthreads();
  const float* W2p = aW2 + (size_t)t0 * 256 * 52;
  for (int idx = tid; idx < 16 * 52; idx += 256) {
    int s = idx / 52, d = idx - s * 52;
    float a = ab2[t0 * 52 + d];
    for (int i = 0; i < 256; ++i) a += h1[s][i] * W2p[i * 52 + d];
    int sg = st * 16 + s;
    float m = inp[((size_t)b * 512 + sg) * 520 + 468 + d];
    out[((size_t)b * 512 + sg) * 52 + d] = (m != 0.f) ? a : 0.f;
  }
}

// ---------- launch ----------
extern "C" void kernel_launch(void* const* d_in, const int* in_sizes, int n_in,
                              void* d_out, int out_size, void* d_ws, size_t ws_size,
                              hipStream_t stream) {
  const float* inputs = (const float*)d_in[0];
  const float* state  = (const float*)d_in[1];
  const int*   ptypes = (const int*)d_in[2];
  const float* emb_W  = (const float*)d_in[3];
  const float* emb_b  = (const float*)d_in[4];
  const float* W_ih   = (const float*)d_in[5];
  const float* W_hh   = (const float*)d_in[6];
  const float* b_ih   = (const float*)d_in[7];
  const float* b_hh   = (const float*)d_in[8];
  const float* W0     = (const float*)d_in[9];
  const float* a0     = (const float*)d_in[10];
  const float* W1     = (const float*)d_in[11];
  const float* a1     = (const float*)d_in[12];
  const float* aW1    = (const float*)d_in[13];
  const float* ab1    = (const float*)d_in[14];
  const float* aW2    = (const float*)d_in[15];
  const float* ab2    = (const float*)d_in[16];

  char* ws = (char*)d_ws;
  // persistent buffers (peak 202.1 MB)
  unsigned short* emb    = (unsigned short*)(ws + 0);            // 50,331,648 B  [s][r][512] bf16
  float*          gxc    = (float*)(ws + 50331648);              // 37,748,736 B  32-step chunk, f32
  unsigned short* gnn    = (unsigned short*)(ws + 88080384);     // 100,663,296 B
  float*          h_f32  = (float*)(ws + 188743680);             // 393,216 B
  unsigned short* h_bf   = (unsigned short*)(ws + 189136896);    // 393,216 B (2 bufs)
  unsigned short* Wihb   = (unsigned short*)(ws + 189530112);    // 3,145,728 B
  unsigned short* W0t    = (unsigned short*)(ws + 192675840);    // 2,097,152 B
  unsigned short* W1t    = (unsigned short*)(ws + 194772992);    // 1,048,576 B
  unsigned short* Whh_bf = (unsigned short*)(ws + 195821568);    // 6,291,456 B
  int*            bar    = (int*)(ws + 202113024);               // 256 B -> end 202,113,280
  // GAT-phase chunk overlays in [0, 88,080,384) (emb+gxc dead)
  unsigned short* Wh0c = (unsigned short*)(ws + 0);              // 25,165,824 B
  unsigned short* g0c  = (unsigned short*)(ws + 25165824);       // 25,165,824 B
  unsigned short* Wh1c = (unsigned short*)(ws + 50331648);       // 12,582,912 B
  float*          featc = (float*)(ws + 62914560);               //  8,388,608 B -> end 71,303,168

  float* logits = (float*)d_out;
  float* hfin   = (float*)d_out + 16 * 512 * 52;

  // prep
  cast_bf16_kernel<<<6144, 256, 0, stream>>>(W_ih, Wihb, 3072 * 512);
  cast_bf16_kernel<<<12288, 256, 0, stream>>>(W_hh, Whh_bf, 3072 * 1024);
  transpose_cast_kernel<<<4096, 256, 0, stream>>>(W0, W0t, 1024, 256, 4 * 1024 * 256);
  transpose_cast_kernel<<<2048, 256, 0, stream>>>(W1, W1t, 1024, 128, 4 * 1024 * 128);
  cast_bf16_kernel<<<384, 256, 0, stream>>>(state, h_bf, 96 * 1024);
  hipMemcpyAsync(h_f32, state, 96 * 1024 * sizeof(float), hipMemcpyDeviceToDevice, stream);
  hipMemsetAsync(bar, 0, 8, stream);

  embed_kernel<<<dim3(96, 32), 256, 0, stream>>>(inputs, ptypes, emb_W, emb_b, emb);

  // GRU: 16 chunks of 32 steps
  for (int c = 0; c < 16; ++c) {
    gemm_bt<false, true><<<dim3(24, 24), 256, 0, stream>>>(
        emb + (size_t)c * 3072 * 512, Wihb, gxc, b_ih, 3072, 3072, 512);
    gru_chunk<<<64, 256, 0, stream>>>(Whh_bf, gxc, b_hh, h_bf, h_f32, gnn, c * 32, bar);
  }

  // GAT + actor: 4 b-chunks of 4 batches (12288 rows)
  for (int gc = 0; gc < 4; ++gc) {
    const size_t row0 = (size_t)gc * 12288;
    gemm_bt<true, false><<<dim3(96, 8), 256, 0, stream>>>(gnn + row0 * 1024, W0t, Wh0c, nullptr, 12288, 1024, 1024);
    gat0_combine<<<2048, 256, 0, stream>>>(Wh0c, a0, g0c);
    gemm_bt<true, false><<<dim3(96, 4), 256, 0, stream>>>(g0c, W1t, Wh1c, nullptr, 12288, 512, 1024);
    gat1_combine<<<2048, 256, 0, stream>>>(Wh1c, a1, featc);
    actor_kernel<<<dim3(4, 32), 256, 0, stream>>>(featc, ptypes, aW1, ab1, aW2, ab2, inputs,
                                                  logits, gc * 4);
  }
  hipMemcpyAsync(hfin, h_f32, 96 * 1024 * sizeof(float), hipMemcpyDeviceToDevice, stream);
}